// Round 16
// baseline (37.555 us; speedup 1.0000x reference)
//
#include <hip/hip_runtime.h>
#include <math.h>

// Problem constants: N=2048, L=8, D=64, M=N=2048.
#define N_B 2048
#define L_L 8
#define D_D 64

typedef short bf16x8 __attribute__((ext_vector_type(8)));
typedef float f32x4 __attribute__((ext_vector_type(4)));
typedef unsigned short ushort8v __attribute__((ext_vector_type(8)));

#if __has_builtin(__builtin_amdgcn_exp2f)
#define EXP2(x) __builtin_amdgcn_exp2f(x)
#else
#define EXP2(x) exp2f(x)
#endif

// Async global->LDS, 16B per lane. LDS dest is wave-uniform base + lane*16;
// global src is per-lane (pre-swizzled to implement the LDS XOR swizzle).
#define GLOAD_LDS16(g, l)                                                    \
  __builtin_amdgcn_global_load_lds(                                          \
      (const __attribute__((address_space(1))) void*)(g),                    \
      (__attribute__((address_space(3))) void*)(l), 16, 0, 0)

// Split fp32 x into bf16 hi + bf16 lo (RTNE each). hi in high16, lo in low16.
__device__ __forceinline__ unsigned split_bf16_pack(float x) {
  unsigned u = __float_as_uint(x);
  unsigned rb = u + 0x7FFFu + ((u >> 16) & 1u);
  unsigned hbits = rb & 0xFFFF0000u;
  float res = x - __uint_as_float(hbits);
  unsigned u2 = __float_as_uint(res);
  unsigned rb2 = u2 + 0x7FFFu + ((u2 >> 16) & 1u);
  return hbits | (rb2 >> 16);
}

// Split 8 contiguous floats (scaled) into hi/lo ushort8 vectors.
__device__ __forceinline__ void split8(const float* __restrict__ src,
                                       float scale, ushort8v& H, ushort8v& L,
                                       float* ssq) {
  float4 v0 = *(const float4*)(src);
  float4 v1 = *(const float4*)(src + 4);
  float vv[8] = {v0.x, v0.y, v0.z, v0.w, v1.x, v1.y, v1.z, v1.w};
  #pragma unroll
  for (int t = 0; t < 8; ++t) {
    if (ssq) *ssq += vv[t] * vv[t];
    unsigned p = split_bf16_pack(scale * vv[t]);
    H[t] = (unsigned short)(p >> 16);
    L[t] = (unsigned short)(p & 0xFFFF);
  }
}

// Load 16 floats (k0..k0+7, k0+32..k0+39) from a 64-float row, split to frags.
__device__ __forceinline__ void load_split_row(const float* base, int k0,
                                               bf16x8& H0, bf16x8& L0,
                                               bf16x8& H1, bf16x8& L1) {
  float4 a0 = *(const float4*)(base + k0);
  float4 a1 = *(const float4*)(base + k0 + 4);
  float4 b0 = *(const float4*)(base + k0 + 32);
  float4 b1 = *(const float4*)(base + k0 + 36);
  float vv[16] = {a0.x, a0.y, a0.z, a0.w, a1.x, a1.y, a1.z, a1.w,
                  b0.x, b0.y, b0.z, b0.w, b1.x, b1.y, b1.z, b1.w};
  #pragma unroll
  for (int t = 0; t < 8; ++t) {
    unsigned p0 = split_bf16_pack(vv[t]);
    H0[t] = (short)(p0 >> 16); L0[t] = (short)(p0 & 0xFFFF);
    unsigned p1 = split_bf16_pack(vv[8 + t]);
    H1[t] = (short)(p1 >> 16); L1[t] = (short)(p1 & 0xFFFF);
  }
}

// ---------------------------------------------------------------------------
// K1: independent prep work in one launch (proven version, verbatim).
//  bid [0,512):   e-split, XCD-aligned (l = bid&7)
//  bid [512,768): encode (LDS-staged, split from LDS, 6 split-MFMAs)
//  bid [768,784): decW split -> dwh/dwl
// ---------------------------------------------------------------------------
__global__ __launch_bounds__(256) void k1_prep_encode(
    const float* __restrict__ z, const float* __restrict__ e,
    const float* __restrict__ encW, const float* __restrict__ encb,
    const float* __restrict__ decW, const float* __restrict__ lsg,
    float* __restrict__ zm,
    unsigned short* __restrict__ esh, unsigned short* __restrict__ esl,
    float* __restrict__ en2G,
    unsigned short* __restrict__ zhG, unsigned short* __restrict__ zlG,
    float* __restrict__ ezG,
    unsigned short* __restrict__ dwh, unsigned short* __restrict__ dwl) {
  __shared__ __align__(16) float zT[64][68];
  __shared__ __align__(16) float wT[64][68];
  const unsigned bid = blockIdx.x;
  const int tid = threadIdx.x;
  const int lane = tid & 63;
  const int wave = tid >> 6;
  const int bm = lane & 15;
  const int kg = lane >> 4;
  const int k0 = kg << 3;

  const float ls = lsg[0];
  const float sig = __expf(ls);
  const float ap = (-1.0f / (2.0f * sig * sig)) * 1.4426950408889634f;
  const float se = -2.0f * ap;

  if (bid < 512) {
    const int l = bid & 7;
    const int sub = bid >> 3;                  // 0..63
    const int row = l * N_B + (sub << 5) + (tid >> 3);
    const int c = (tid & 7) << 3;
    size_t off = (size_t)row * 64 + c;
    ushort8v H, L;
    float ssq = 0.f;
    split8(e + off, se, H, L, &ssq);
    *(ushort8v*)(esh + off) = H;
    *(ushort8v*)(esl + off) = L;
    ssq += __shfl_xor(ssq, 1);
    ssq += __shfl_xor(ssq, 2);
    ssq += __shfl_xor(ssq, 4);
    if ((tid & 7) == 0) en2G[row] = ssq;
  } else if (bid < 768) {
    const int eb = bid - 512;
    const int l = eb & 7;
    const int nt = eb >> 3;
    const int n0 = nt << 6;
    {
      int r = tid >> 2, q = (tid & 3) << 4;
      const float4* zsrc = (const float4*)(z + (size_t)(n0 + r) * 64 + q);
      const float4* wsrc = (const float4*)(encW + (size_t)(l * 64 + r) * 64 + q);
      #pragma unroll
      for (int j = 0; j < 4; ++j) {
        *(float4*)&zT[r][q + j * 4] = zsrc[j];
        *(float4*)&wT[r][q + j * 4] = wsrc[j];
      }
    }
    __syncthreads();
    bf16x8 Bh0[4], Bh1[4], Bl0[4], Bl1[4];
    #pragma unroll
    for (int ms = 0; ms < 4; ++ms)
      load_split_row(&wT[ms * 16 + bm][0], k0,
                     Bh0[ms], Bl0[ms], Bh1[ms], Bl1[ms]);
    bf16x8 ah0, al0, ah1, al1;
    load_split_row(&zT[(wave << 4) + bm][0], k0, ah0, al0, ah1, al1);

    float sq[4] = {0.f, 0.f, 0.f, 0.f};
    #pragma unroll
    for (int ms = 0; ms < 4; ++ms) {
      float bi = encb[l * 64 + ms * 16 + bm];
      f32x4 acc = {bi, bi, bi, bi};
      acc = __builtin_amdgcn_mfma_f32_16x16x32_bf16(ah0, Bh0[ms], acc, 0, 0, 0);
      acc = __builtin_amdgcn_mfma_f32_16x16x32_bf16(ah1, Bh1[ms], acc, 0, 0, 0);
      acc = __builtin_amdgcn_mfma_f32_16x16x32_bf16(al0, Bh0[ms], acc, 0, 0, 0);
      acc = __builtin_amdgcn_mfma_f32_16x16x32_bf16(al1, Bh1[ms], acc, 0, 0, 0);
      acc = __builtin_amdgcn_mfma_f32_16x16x32_bf16(ah0, Bl0[ms], acc, 0, 0, 0);
      acc = __builtin_amdgcn_mfma_f32_16x16x32_bf16(ah1, Bl1[ms], acc, 0, 0, 0);
      #pragma unroll
      for (int r = 0; r < 4; ++r) {
        float v = acc[r];
        int nr = n0 + (wave << 4) + (kg << 2) + r;
        size_t idx = ((size_t)(l * N_B + nr)) * 64 + (ms << 4) + bm;
        zm[idx] = v;
        unsigned p = split_bf16_pack(v);
        zhG[idx] = (unsigned short)(p >> 16);
        zlG[idx] = (unsigned short)(p & 0xFFFF);
        sq[r] += v * v;
      }
    }
    #pragma unroll
    for (int r = 0; r < 4; ++r) {
      float s = sq[r];
      s += __shfl_xor(s, 1);
      s += __shfl_xor(s, 2);
      s += __shfl_xor(s, 4);
      s += __shfl_xor(s, 8);
      if (bm == 0)
        ezG[l * N_B + n0 + (wave << 4) + (kg << 2) + r] = EXP2(ap * s);
    }
  } else {
    int t = (bid - 768) * 256 + tid;  // 0..4095
    size_t off = (size_t)t * 8;
    ushort8v H, L;
    split8(decW + off, 1.0f, H, L, nullptr);
    *(ushort8v*)(dwh + off) = H;
    *(ushort8v*)(dwl + off) = L;
  }
}

// ---------------------------------------------------------------------------
// K2 (lse): grid 512 = l(8) x mt(32) x nb(2), XCD-swizzled (one l per XCD).
// BARRIER-FREE K-loop: each wave stages and reads ONLY its own 16-row LDS
// quarter, so cross-wave sync is unnecessary. Pipeline ordering is enforced
// purely by counted vmcnt (T4): per iter issue {4 global_load_lds + 1 ez} for
// c+1, then s_waitcnt vmcnt(5) retires exactly tile c's group. No vmcnt(0)
// drain in the loop.  XOR swizzle on the GLOBAL src (rule #21).
// partial[(l*2048+m)*2+nb] = sum_n ez_n * exp2( (-2ap) z_n.e_m )
// ---------------------------------------------------------------------------
__global__ __launch_bounds__(256, 4) void lse_kernel(
    const unsigned short* __restrict__ zhG, const unsigned short* __restrict__ zlG,
    const unsigned short* __restrict__ esh, const unsigned short* __restrict__ esl,
    const float* __restrict__ ezG, float* __restrict__ partials) {
  __shared__ __align__(16) unsigned short zbh[2][4096];  // [buf][row*64+elem^]
  __shared__ __align__(16) unsigned short zbl[2][4096];
  __shared__ float red[4][64];
  const int wgid = (blockIdx.x & 7) * 64 + (blockIdx.x >> 3);  // XCD swizzle
  const int l = wgid >> 6;
  const int mt = (wgid >> 1) & 31;
  const int nb = wgid & 1;
  const int m0 = mt << 6;
  const int tid = threadIdx.x;
  const int lane = tid & 63;
  const int wave = tid >> 6;
  const int bm = lane & 15;
  const int kg = lane >> 4;
  const int k0 = kg << 3;

  // ---- B fragments: pre-split scaled e rows (held in registers) ----
  bf16x8 Bh0[4], Bh1[4], Bl0[4], Bl1[4];
  #pragma unroll
  for (int ms = 0; ms < 4; ++ms) {
    size_t base = ((size_t)(l * N_B) + m0 + ms * 16 + bm) * 64 + k0;
    Bh0[ms] = *(const bf16x8*)(esh + base);
    Bh1[ms] = *(const bf16x8*)(esh + base + 32);
    Bl0[ms] = *(const bf16x8*)(esl + base);
    Bl1[ms] = *(const bf16x8*)(esl + base + 32);
  }

  // ---- staging geometry (constant across c) ----
  const int srow0 = (wave << 4) + (lane >> 3);
  const size_t g0 = (size_t)srow0 * 64 + (((lane & 7) ^ (lane >> 3)) << 3);
  const size_t g1 = g0 + 8 * 64;  // +8 rows, same swizzle (row&7 unchanged)
  const int ldsb0 = (wave << 4) * 64;           // elems, uniform per wave
  const unsigned short* zhT =
      zhG + ((size_t)(l * N_B) + (nb << 10)) * 64;  // tile base
  const unsigned short* zlT = zlG + ((size_t)(l * N_B) + (nb << 10)) * 64;

  auto stage = [&](int b, int c) {
    size_t toff = (size_t)(c << 6) * 64;  // c*64 rows
    GLOAD_LDS16(zhT + toff + g0, &zbh[b][ldsb0]);
    GLOAD_LDS16(zhT + toff + g1, &zbh[b][ldsb0 + 512]);
    GLOAD_LDS16(zlT + toff + g0, &zbl[b][ldsb0]);
    GLOAD_LDS16(zlT + toff + g1, &zbl[b][ldsb0 + 512]);
  };

  // ---- A-fragment LDS read offsets (XOR-swizzled) ----
  const int arow = (wave << 4) + bm;
  const int sw = (bm & 7) << 3;
  const int o0 = arow * 64 + ((kg << 3) ^ sw);
  const int o1 = arow * 64 + (((kg << 3) + 32) ^ sw);

  float sums[4] = {0.f, 0.f, 0.f, 0.f};
  const float* ezQ = ezG + l * N_B + (nb << 10) + (wave << 4) + (kg << 2);

  stage(0, 0);
  f32x4 ezv = *(const f32x4*)(ezQ);   // counts as tile-0 group's 5th VMEM op

  int cur = 0;
  #pragma unroll 1
  for (int c = 0; c < 16; ++c) {
    f32x4 eznext = ezv;
    if (c < 15) {
      stage(cur ^ 1, c + 1);                       // 4 VMEM (async to LDS)
      eznext = *(const f32x4*)(ezQ + ((c + 1) << 6));  // 1 VMEM
      // oldest-5 (tile c's group) retired; c+1's 5 stay in flight.
      asm volatile("s_waitcnt vmcnt(5)" ::: "memory");
    } else {
      asm volatile("s_waitcnt vmcnt(0)" ::: "memory");
    }
    bf16x8 ah0 = *(const bf16x8*)&zbh[cur][o0];
    bf16x8 ah1 = *(const bf16x8*)&zbh[cur][o1];
    bf16x8 al0 = *(const bf16x8*)&zbl[cur][o0];
    bf16x8 al1 = *(const bf16x8*)&zbl[cur][o1];
    #pragma unroll
    for (int ms = 0; ms < 4; ++ms) {
      f32x4 acc = {0.f, 0.f, 0.f, 0.f};
      acc = __builtin_amdgcn_mfma_f32_16x16x32_bf16(ah0, Bh0[ms], acc, 0, 0, 0);
      acc = __builtin_amdgcn_mfma_f32_16x16x32_bf16(ah1, Bh1[ms], acc, 0, 0, 0);
      acc = __builtin_amdgcn_mfma_f32_16x16x32_bf16(al0, Bh0[ms], acc, 0, 0, 0);
      acc = __builtin_amdgcn_mfma_f32_16x16x32_bf16(al1, Bh1[ms], acc, 0, 0, 0);
      acc = __builtin_amdgcn_mfma_f32_16x16x32_bf16(ah0, Bl0[ms], acc, 0, 0, 0);
      acc = __builtin_amdgcn_mfma_f32_16x16x32_bf16(ah1, Bl1[ms], acc, 0, 0, 0);
      sums[ms] = fmaf(ezv[0], EXP2(acc[0]), sums[ms]);
      sums[ms] = fmaf(ezv[1], EXP2(acc[1]), sums[ms]);
      sums[ms] = fmaf(ezv[2], EXP2(acc[2]), sums[ms]);
      sums[ms] = fmaf(ezv[3], EXP2(acc[3]), sums[ms]);
    }
    ezv = eznext;
    cur ^= 1;
  }

  #pragma unroll
  for (int ms = 0; ms < 4; ++ms) {
    float s = sums[ms];
    s += __shfl_xor(s, 16);
    s += __shfl_xor(s, 32);
    if (lane < 16) red[wave][ms * 16 + lane] = s;
  }
  __syncthreads();
  if (tid < 64) {
    float S = red[0][tid] + red[1][tid] + red[2][tid] + red[3][tid];
    partials[((((size_t)(l * N_B)) + m0 + tid) << 1) + nb] = S;
  }
}

// ---------------------------------------------------------------------------
// K3: zdec (bid<128) || whole finalize (bid==128). Verbatim round-15 version.
// ---------------------------------------------------------------------------
__global__ __launch_bounds__(256) void k3_zdec_finalize(
    const unsigned short* __restrict__ zhG, const unsigned short* __restrict__ zlG,
    const unsigned short* __restrict__ dwh, const unsigned short* __restrict__ dwl,
    const float* __restrict__ decb,
    const float* __restrict__ partials, const float* __restrict__ en2G,
    const float* __restrict__ lsg,
    float* __restrict__ zdec, float* __restrict__ out_scalar) {
  __shared__ __align__(16) unsigned char smem_raw[16384];
  const unsigned bid = blockIdx.x;
  const int tid = threadIdx.x;
  const int lane = tid & 63;
  const int wave = tid >> 6;
  const int bm = lane & 15;
  const int kg = lane >> 4;
  const int k0 = kg << 3;

  if (bid < 128) {
    f32x4(*redq)[4][64] = (f32x4(*)[4][64])smem_raw;
    const int n0 = bid << 4;
    f32x4 acc[4] = {{0.f, 0.f, 0.f, 0.f}, {0.f, 0.f, 0.f, 0.f},
                    {0.f, 0.f, 0.f, 0.f}, {0.f, 0.f, 0.f, 0.f}};
    #pragma unroll
    for (int jj = 0; jj < 4; ++jj) {
      int j = (wave << 2) + jj;
      int l = j >> 1;
      int off = ((j & 1) << 5) + k0;
      size_t ab = ((size_t)(l * N_B + n0 + bm)) * 64 + off;
      bf16x8 ah = *(const bf16x8*)(zhG + ab);
      bf16x8 al = *(const bf16x8*)(zlG + ab);
      #pragma unroll
      for (int ms = 0; ms < 4; ++ms) {
        int d = (ms << 4) + bm;
        size_t bb = (size_t)d * 512 + (j << 5) + k0;
        bf16x8 bh = *(const bf16x8*)(dwh + bb);
        bf16x8 bl = *(const bf16x8*)(dwl + bb);
        acc[ms] = __builtin_amdgcn_mfma_f32_16x16x32_bf16(ah, bh, acc[ms], 0, 0, 0);
        acc[ms] = __builtin_amdgcn_mfma_f32_16x16x32_bf16(al, bh, acc[ms], 0, 0, 0);
        acc[ms] = __builtin_amdgcn_mfma_f32_16x16x32_bf16(ah, bl, acc[ms], 0, 0, 0);
      }
    }
    #pragma unroll
    for (int ms = 0; ms < 4; ++ms) redq[wave][ms][lane] = acc[ms];
    __syncthreads();
    if (wave == 0) {
      #pragma unroll
      for (int ms = 0; ms < 4; ++ms) {
        f32x4 s = redq[0][ms][lane];
        #pragma unroll
        for (int w = 1; w < 4; ++w) {
          f32x4 t = redq[w][ms][lane];
          s[0] += t[0]; s[1] += t[1]; s[2] += t[2]; s[3] += t[3];
        }
        float bd = decb[(ms << 4) + bm];
        #pragma unroll
        for (int r = 0; r < 4; ++r)
          zdec[(size_t)(n0 + (kg << 2) + r) * 64 + (ms << 4) + bm] = s[r] + bd;
      }
    }
  } else {
    float* buf = (float*)smem_raw;
    const float ls = lsg[0];
    const float sig = __expf(ls);
    const float ap = (-1.0f / (2.0f * sig * sig)) * 1.4426950408889634f;
    float local = 0.f;
    #pragma unroll 4
    for (int i = 0; i < 32; ++i) {
      int idx2 = (tid + (i << 8)) << 1;  // rows 2t, partials [row][2]
      f32x4 p = *(const f32x4*)(partials + idx2 * 2);  // rows 2t..2t+1
      float2 e2 = *(const float2*)(en2G + idx2);
      local += ap * e2.x + __log2f(p[0] + p[1]);
      local += ap * e2.y + __log2f(p[2] + p[3]);
    }
    #pragma unroll
    for (int off = 32; off; off >>= 1) local += __shfl_down(local, off);
    if (lane == 0) buf[wave] = local;
    __syncthreads();
    if (tid == 0) {
      float t = buf[0] + buf[1] + buf[2] + buf[3];
      float total = 0.69314718055994531f * t;
      float val = -total / (float)(L_L * N_B)
                + 0.5f * (float)D_D * (2.0f * ls - 1.0f)
                + logf((float)N_B);
      *out_scalar = val;
    }
  }
}

extern "C" void kernel_launch(void* const* d_in, const int* in_sizes, int n_in,
                              void* d_out, int out_size, void* d_ws, size_t ws_size,
                              hipStream_t stream) {
  const float* z    = (const float*)d_in[0];
  const float* e    = (const float*)d_in[1];
  const float* encW = (const float*)d_in[2];
  const float* encb = (const float*)d_in[3];
  const float* decW = (const float*)d_in[4];
  const float* decb = (const float*)d_in[5];
  const float* lsg  = (const float*)d_in[6];

  float* out    = (float*)d_out;
  float* zdec   = out;                                // [2048*64]
  float* zmulti = out + N_B * D_D;                    // [8*2048*64]
  float* lse    = out + N_B * D_D + L_L * N_B * D_D;  // [1]

  float* partials = (float*)d_ws;                     // [16384*2]
  float* ez       = partials + 65536;                 // [16384]
  float* en2      = ez + 16384;                       // [16384]
  unsigned short* us = (unsigned short*)(en2 + 16384);
  unsigned short* esh = us;                 // [1048576]
  unsigned short* esl = esh + 1048576;
  unsigned short* zh  = esl + 1048576;      // [1048576]
  unsigned short* zl  = zh + 1048576;
  unsigned short* dwh = zl + 1048576;       // [32768]
  unsigned short* dwl = dwh + 32768;

  k1_prep_encode<<<784, 256, 0, stream>>>(z, e, encW, encb, decW, lsg,
                                          zmulti, esh, esl, en2,
                                          zh, zl, ez, dwh, dwl);
  lse_kernel<<<512, 256, 0, stream>>>(zh, zl, esh, esl, ez, partials);
  k3_zdec_finalize<<<129, 256, 0, stream>>>(zh, zl, dwh, dwl, decb,
                                            partials, en2, lsg,
                                            zdec, lse);
}

// Round 17
// 34.648 us; speedup vs baseline: 1.0839x; 1.0839x over previous
//
#include <hip/hip_runtime.h>
#include <math.h>

// Problem constants: N=2048, L=8, D=64, M=N=2048.
#define N_B 2048
#define L_L 8
#define D_D 64

typedef short bf16x8 __attribute__((ext_vector_type(8)));
typedef float f32x4 __attribute__((ext_vector_type(4)));
typedef unsigned short ushort8v __attribute__((ext_vector_type(8)));

#if __has_builtin(__builtin_amdgcn_exp2f)
#define EXP2(x) __builtin_amdgcn_exp2f(x)
#else
#define EXP2(x) exp2f(x)
#endif

// Async global->LDS, 16B per lane. LDS dest is wave-uniform base + lane*16;
// global src is per-lane (pre-swizzled to implement the LDS XOR swizzle).
#define GLOAD_LDS16(g, l)                                                    \
  __builtin_amdgcn_global_load_lds(                                          \
      (const __attribute__((address_space(1))) void*)(g),                    \
      (__attribute__((address_space(3))) void*)(l), 16, 0, 0)

// Split fp32 x into bf16 hi + bf16 lo (RTNE each). hi in high16, lo in low16.
__device__ __forceinline__ unsigned split_bf16_pack(float x) {
  unsigned u = __float_as_uint(x);
  unsigned rb = u + 0x7FFFu + ((u >> 16) & 1u);
  unsigned hbits = rb & 0xFFFF0000u;
  float res = x - __uint_as_float(hbits);
  unsigned u2 = __float_as_uint(res);
  unsigned rb2 = u2 + 0x7FFFu + ((u2 >> 16) & 1u);
  return hbits | (rb2 >> 16);
}

// Split 8 contiguous floats (scaled) into hi/lo ushort8 vectors.
__device__ __forceinline__ void split8(const float* __restrict__ src,
                                       float scale, ushort8v& H, ushort8v& L,
                                       float* ssq) {
  float4 v0 = *(const float4*)(src);
  float4 v1 = *(const float4*)(src + 4);
  float vv[8] = {v0.x, v0.y, v0.z, v0.w, v1.x, v1.y, v1.z, v1.w};
  #pragma unroll
  for (int t = 0; t < 8; ++t) {
    if (ssq) *ssq += vv[t] * vv[t];
    unsigned p = split_bf16_pack(scale * vv[t]);
    H[t] = (unsigned short)(p >> 16);
    L[t] = (unsigned short)(p & 0xFFFF);
  }
}

// Load 16 floats (k0..k0+7, k0+32..k0+39) from a 64-float row, split to frags.
__device__ __forceinline__ void load_split_row(const float* base, int k0,
                                               bf16x8& H0, bf16x8& L0,
                                               bf16x8& H1, bf16x8& L1) {
  float4 a0 = *(const float4*)(base + k0);
  float4 a1 = *(const float4*)(base + k0 + 4);
  float4 b0 = *(const float4*)(base + k0 + 32);
  float4 b1 = *(const float4*)(base + k0 + 36);
  float vv[16] = {a0.x, a0.y, a0.z, a0.w, a1.x, a1.y, a1.z, a1.w,
                  b0.x, b0.y, b0.z, b0.w, b1.x, b1.y, b1.z, b1.w};
  #pragma unroll
  for (int t = 0; t < 8; ++t) {
    unsigned p0 = split_bf16_pack(vv[t]);
    H0[t] = (short)(p0 >> 16); L0[t] = (short)(p0 & 0xFFFF);
    unsigned p1 = split_bf16_pack(vv[8 + t]);
    H1[t] = (short)(p1 >> 16); L1[t] = (short)(p1 & 0xFFFF);
  }
}

// ---------------------------------------------------------------------------
// K1: independent prep work in one launch — 400 blocks (was 784): e-split
// grid-strided 4x to amortize block ramp.
//  bid [0,128):   e-split, 128 rows/block over 4 iters, XCD-aligned (l=bid&7)
//  bid [128,384): encode (LDS-staged, split from LDS, 6 split-MFMAs)
//  bid [384,400): decW split -> dwh/dwl
// ---------------------------------------------------------------------------
__global__ __launch_bounds__(256) void k1_prep_encode(
    const float* __restrict__ z, const float* __restrict__ e,
    const float* __restrict__ encW, const float* __restrict__ encb,
    const float* __restrict__ decW, const float* __restrict__ lsg,
    float* __restrict__ zm,
    unsigned short* __restrict__ esh, unsigned short* __restrict__ esl,
    float* __restrict__ en2G,
    unsigned short* __restrict__ zhG, unsigned short* __restrict__ zlG,
    float* __restrict__ ezG,
    unsigned short* __restrict__ dwh, unsigned short* __restrict__ dwl) {
  __shared__ __align__(16) float zT[64][68];
  __shared__ __align__(16) float wT[64][68];
  const unsigned bid = blockIdx.x;
  const int tid = threadIdx.x;
  const int lane = tid & 63;
  const int wave = tid >> 6;
  const int bm = lane & 15;
  const int kg = lane >> 4;
  const int k0 = kg << 3;

  const float ls = lsg[0];
  const float sig = __expf(ls);
  const float ap = (-1.0f / (2.0f * sig * sig)) * 1.4426950408889634f;
  const float se = -2.0f * ap;

  if (bid < 128) {
    // e-split: block covers 128 rows of latent l = bid&7 (XCD l), 4 iters.
    const int l = bid & 7;
    const int sub = bid >> 3;                  // 0..15
    const int rbase = l * N_B + (sub << 7);    // 128 rows
    const int c = (tid & 7) << 3;
    #pragma unroll
    for (int it = 0; it < 4; ++it) {
      const int row = rbase + (it << 5) + (tid >> 3);
      size_t off = (size_t)row * 64 + c;
      ushort8v H, L;
      float ssq = 0.f;
      split8(e + off, se, H, L, &ssq);
      *(ushort8v*)(esh + off) = H;
      *(ushort8v*)(esl + off) = L;
      ssq += __shfl_xor(ssq, 1);
      ssq += __shfl_xor(ssq, 2);
      ssq += __shfl_xor(ssq, 4);
      if ((tid & 7) == 0) en2G[row] = ssq;
    }
  } else if (bid < 384) {
    const int eb = bid - 128;
    const int l = eb & 7;
    const int nt = eb >> 3;
    const int n0 = nt << 6;
    {
      int r = tid >> 2, q = (tid & 3) << 4;
      const float4* zsrc = (const float4*)(z + (size_t)(n0 + r) * 64 + q);
      const float4* wsrc = (const float4*)(encW + (size_t)(l * 64 + r) * 64 + q);
      #pragma unroll
      for (int j = 0; j < 4; ++j) {
        *(float4*)&zT[r][q + j * 4] = zsrc[j];
        *(float4*)&wT[r][q + j * 4] = wsrc[j];
      }
    }
    __syncthreads();
    bf16x8 Bh0[4], Bh1[4], Bl0[4], Bl1[4];
    #pragma unroll
    for (int ms = 0; ms < 4; ++ms)
      load_split_row(&wT[ms * 16 + bm][0], k0,
                     Bh0[ms], Bl0[ms], Bh1[ms], Bl1[ms]);
    bf16x8 ah0, al0, ah1, al1;
    load_split_row(&zT[(wave << 4) + bm][0], k0, ah0, al0, ah1, al1);

    float sq[4] = {0.f, 0.f, 0.f, 0.f};
    #pragma unroll
    for (int ms = 0; ms < 4; ++ms) {
      float bi = encb[l * 64 + ms * 16 + bm];
      f32x4 acc = {bi, bi, bi, bi};
      acc = __builtin_amdgcn_mfma_f32_16x16x32_bf16(ah0, Bh0[ms], acc, 0, 0, 0);
      acc = __builtin_amdgcn_mfma_f32_16x16x32_bf16(ah1, Bh1[ms], acc, 0, 0, 0);
      acc = __builtin_amdgcn_mfma_f32_16x16x32_bf16(al0, Bh0[ms], acc, 0, 0, 0);
      acc = __builtin_amdgcn_mfma_f32_16x16x32_bf16(al1, Bh1[ms], acc, 0, 0, 0);
      acc = __builtin_amdgcn_mfma_f32_16x16x32_bf16(ah0, Bl0[ms], acc, 0, 0, 0);
      acc = __builtin_amdgcn_mfma_f32_16x16x32_bf16(ah1, Bl1[ms], acc, 0, 0, 0);
      #pragma unroll
      for (int r = 0; r < 4; ++r) {
        float v = acc[r];
        int nr = n0 + (wave << 4) + (kg << 2) + r;
        size_t idx = ((size_t)(l * N_B + nr)) * 64 + (ms << 4) + bm;
        zm[idx] = v;
        unsigned p = split_bf16_pack(v);
        zhG[idx] = (unsigned short)(p >> 16);
        zlG[idx] = (unsigned short)(p & 0xFFFF);
        sq[r] += v * v;
      }
    }
    #pragma unroll
    for (int r = 0; r < 4; ++r) {
      float s = sq[r];
      s += __shfl_xor(s, 1);
      s += __shfl_xor(s, 2);
      s += __shfl_xor(s, 4);
      s += __shfl_xor(s, 8);
      if (bm == 0)
        ezG[l * N_B + n0 + (wave << 4) + (kg << 2) + r] = EXP2(ap * s);
    }
  } else {
    int t = (bid - 384) * 256 + tid;  // 0..4095
    size_t off = (size_t)t * 8;
    ushort8v H, L;
    split8(decW + off, 1.0f, H, L, nullptr);
    *(ushort8v*)(dwh + off) = H;
    *(ushort8v*)(dwl + off) = L;
  }
}

// ---------------------------------------------------------------------------
// K2 (lse): grid 512 = l(8) x mt(32) x nb(2), XCD-swizzled (one l per XCD).
// PROVEN round-15 version (36.2 µs): double-buffered global_load_lds staging,
// one __syncthreads per c-iter, XOR swizzle on the GLOBAL src (rule #21).
// partial[(l*2048+m)*2+nb] = sum_n ez_n * exp2( (-2ap) z_n.e_m )
// ---------------------------------------------------------------------------
__global__ __launch_bounds__(256, 4) void lse_kernel(
    const unsigned short* __restrict__ zhG, const unsigned short* __restrict__ zlG,
    const unsigned short* __restrict__ esh, const unsigned short* __restrict__ esl,
    const float* __restrict__ ezG, float* __restrict__ partials) {
  __shared__ __align__(16) unsigned short zbh[2][4096];  // [buf][row*64+elem^]
  __shared__ __align__(16) unsigned short zbl[2][4096];
  __shared__ float red[4][64];
  const int wgid = (blockIdx.x & 7) * 64 + (blockIdx.x >> 3);  // XCD swizzle
  const int l = wgid >> 6;
  const int mt = (wgid >> 1) & 31;
  const int nb = wgid & 1;
  const int m0 = mt << 6;
  const int tid = threadIdx.x;
  const int lane = tid & 63;
  const int wave = tid >> 6;
  const int bm = lane & 15;
  const int kg = lane >> 4;
  const int k0 = kg << 3;

  // ---- B fragments: pre-split scaled e rows (held in registers) ----
  bf16x8 Bh0[4], Bh1[4], Bl0[4], Bl1[4];
  #pragma unroll
  for (int ms = 0; ms < 4; ++ms) {
    size_t base = ((size_t)(l * N_B) + m0 + ms * 16 + bm) * 64 + k0;
    Bh0[ms] = *(const bf16x8*)(esh + base);
    Bh1[ms] = *(const bf16x8*)(esh + base + 32);
    Bl0[ms] = *(const bf16x8*)(esl + base);
    Bl1[ms] = *(const bf16x8*)(esl + base + 32);
  }

  // ---- staging geometry (constant across c) ----
  const int srow0 = (wave << 4) + (lane >> 3);
  const size_t g0 = (size_t)srow0 * 64 + (((lane & 7) ^ (lane >> 3)) << 3);
  const size_t g1 = g0 + 8 * 64;  // +8 rows, same swizzle (row&7 unchanged)
  const int ldsb0 = (wave << 4) * 64;           // elems, uniform per wave
  const unsigned short* zhT =
      zhG + ((size_t)(l * N_B) + (nb << 10)) * 64;  // tile base
  const unsigned short* zlT = zlG + ((size_t)(l * N_B) + (nb << 10)) * 64;

  auto stage = [&](int b, int c) {
    size_t toff = (size_t)(c << 6) * 64;  // c*64 rows
    GLOAD_LDS16(zhT + toff + g0, &zbh[b][ldsb0]);
    GLOAD_LDS16(zhT + toff + g1, &zbh[b][ldsb0 + 512]);
    GLOAD_LDS16(zlT + toff + g0, &zbl[b][ldsb0]);
    GLOAD_LDS16(zlT + toff + g1, &zbl[b][ldsb0 + 512]);
  };

  // ---- A-fragment LDS read offsets (XOR-swizzled) ----
  const int arow = (wave << 4) + bm;
  const int sw = (bm & 7) << 3;
  const int o0 = arow * 64 + ((kg << 3) ^ sw);
  const int o1 = arow * 64 + (((kg << 3) + 32) ^ sw);

  float sums[4] = {0.f, 0.f, 0.f, 0.f};
  const float* ezQ = ezG + l * N_B + (nb << 10) + (wave << 4) + (kg << 2);

  stage(0, 0);
  f32x4 ezv = *(const f32x4*)(ezQ);

  int cur = 0;
  #pragma unroll 1
  for (int c = 0; c < 16; ++c) {
    __syncthreads();  // tile c staged; prior-iter LDS reads retired
    bf16x8 ah0 = *(const bf16x8*)&zbh[cur][o0];
    bf16x8 ah1 = *(const bf16x8*)&zbh[cur][o1];
    bf16x8 al0 = *(const bf16x8*)&zbl[cur][o0];
    bf16x8 al1 = *(const bf16x8*)&zbl[cur][o1];
    f32x4 eznext = ezv;
    if (c < 15) {
      stage(cur ^ 1, c + 1);          // async; drains at next iter's barrier
      eznext = *(const f32x4*)(ezQ + ((c + 1) << 6));
    }
    #pragma unroll
    for (int ms = 0; ms < 4; ++ms) {
      f32x4 acc = {0.f, 0.f, 0.f, 0.f};
      acc = __builtin_amdgcn_mfma_f32_16x16x32_bf16(ah0, Bh0[ms], acc, 0, 0, 0);
      acc = __builtin_amdgcn_mfma_f32_16x16x32_bf16(ah1, Bh1[ms], acc, 0, 0, 0);
      acc = __builtin_amdgcn_mfma_f32_16x16x32_bf16(al0, Bh0[ms], acc, 0, 0, 0);
      acc = __builtin_amdgcn_mfma_f32_16x16x32_bf16(al1, Bh1[ms], acc, 0, 0, 0);
      acc = __builtin_amdgcn_mfma_f32_16x16x32_bf16(ah0, Bl0[ms], acc, 0, 0, 0);
      acc = __builtin_amdgcn_mfma_f32_16x16x32_bf16(ah1, Bl1[ms], acc, 0, 0, 0);
      sums[ms] = fmaf(ezv[0], EXP2(acc[0]), sums[ms]);
      sums[ms] = fmaf(ezv[1], EXP2(acc[1]), sums[ms]);
      sums[ms] = fmaf(ezv[2], EXP2(acc[2]), sums[ms]);
      sums[ms] = fmaf(ezv[3], EXP2(acc[3]), sums[ms]);
    }
    ezv = eznext;
    cur ^= 1;
  }

  #pragma unroll
  for (int ms = 0; ms < 4; ++ms) {
    float s = sums[ms];
    s += __shfl_xor(s, 16);
    s += __shfl_xor(s, 32);
    if (lane < 16) red[wave][ms * 16 + lane] = s;
  }
  __syncthreads();
  if (tid < 64) {
    float S = red[0][tid] + red[1][tid] + red[2][tid] + red[3][tid];
    partials[((((size_t)(l * N_B)) + m0 + tid) << 1) + nb] = S;
  }
}

// ---------------------------------------------------------------------------
// K3: zdec (bid<128) || whole finalize (bid==128). Verbatim round-15 version.
// ---------------------------------------------------------------------------
__global__ __launch_bounds__(256) void k3_zdec_finalize(
    const unsigned short* __restrict__ zhG, const unsigned short* __restrict__ zlG,
    const unsigned short* __restrict__ dwh, const unsigned short* __restrict__ dwl,
    const float* __restrict__ decb,
    const float* __restrict__ partials, const float* __restrict__ en2G,
    const float* __restrict__ lsg,
    float* __restrict__ zdec, float* __restrict__ out_scalar) {
  __shared__ __align__(16) unsigned char smem_raw[16384];
  const unsigned bid = blockIdx.x;
  const int tid = threadIdx.x;
  const int lane = tid & 63;
  const int wave = tid >> 6;
  const int bm = lane & 15;
  const int kg = lane >> 4;
  const int k0 = kg << 3;

  if (bid < 128) {
    f32x4(*redq)[4][64] = (f32x4(*)[4][64])smem_raw;
    const int n0 = bid << 4;
    f32x4 acc[4] = {{0.f, 0.f, 0.f, 0.f}, {0.f, 0.f, 0.f, 0.f},
                    {0.f, 0.f, 0.f, 0.f}, {0.f, 0.f, 0.f, 0.f}};
    #pragma unroll
    for (int jj = 0; jj < 4; ++jj) {
      int j = (wave << 2) + jj;
      int l = j >> 1;
      int off = ((j & 1) << 5) + k0;
      size_t ab = ((size_t)(l * N_B + n0 + bm)) * 64 + off;
      bf16x8 ah = *(const bf16x8*)(zhG + ab);
      bf16x8 al = *(const bf16x8*)(zlG + ab);
      #pragma unroll
      for (int ms = 0; ms < 4; ++ms) {
        int d = (ms << 4) + bm;
        size_t bb = (size_t)d * 512 + (j << 5) + k0;
        bf16x8 bh = *(const bf16x8*)(dwh + bb);
        bf16x8 bl = *(const bf16x8*)(dwl + bb);
        acc[ms] = __builtin_amdgcn_mfma_f32_16x16x32_bf16(ah, bh, acc[ms], 0, 0, 0);
        acc[ms] = __builtin_amdgcn_mfma_f32_16x16x32_bf16(al, bh, acc[ms], 0, 0, 0);
        acc[ms] = __builtin_amdgcn_mfma_f32_16x16x32_bf16(ah, bl, acc[ms], 0, 0, 0);
      }
    }
    #pragma unroll
    for (int ms = 0; ms < 4; ++ms) redq[wave][ms][lane] = acc[ms];
    __syncthreads();
    if (wave == 0) {
      #pragma unroll
      for (int ms = 0; ms < 4; ++ms) {
        f32x4 s = redq[0][ms][lane];
        #pragma unroll
        for (int w = 1; w < 4; ++w) {
          f32x4 t = redq[w][ms][lane];
          s[0] += t[0]; s[1] += t[1]; s[2] += t[2]; s[3] += t[3];
        }
        float bd = decb[(ms << 4) + bm];
        #pragma unroll
        for (int r = 0; r < 4; ++r)
          zdec[(size_t)(n0 + (kg << 2) + r) * 64 + (ms << 4) + bm] = s[r] + bd;
      }
    }
  } else {
    float* buf = (float*)smem_raw;
    const float ls = lsg[0];
    const float sig = __expf(ls);
    const float ap = (-1.0f / (2.0f * sig * sig)) * 1.4426950408889634f;
    float local = 0.f;
    #pragma unroll 4
    for (int i = 0; i < 32; ++i) {
      int idx2 = (tid + (i << 8)) << 1;  // rows 2t, partials [row][2]
      f32x4 p = *(const f32x4*)(partials + idx2 * 2);  // rows 2t..2t+1
      float2 e2 = *(const float2*)(en2G + idx2);
      local += ap * e2.x + __log2f(p[0] + p[1]);
      local += ap * e2.y + __log2f(p[2] + p[3]);
    }
    #pragma unroll
    for (int off = 32; off; off >>= 1) local += __shfl_down(local, off);
    if (lane == 0) buf[wave] = local;
    __syncthreads();
    if (tid == 0) {
      float t = buf[0] + buf[1] + buf[2] + buf[3];
      float total = 0.69314718055994531f * t;
      float val = -total / (float)(L_L * N_B)
                + 0.5f * (float)D_D * (2.0f * ls - 1.0f)
                + logf((float)N_B);
      *out_scalar = val;
    }
  }
}

extern "C" void kernel_launch(void* const* d_in, const int* in_sizes, int n_in,
                              void* d_out, int out_size, void* d_ws, size_t ws_size,
                              hipStream_t stream) {
  const float* z    = (const float*)d_in[0];
  const float* e    = (const float*)d_in[1];
  const float* encW = (const float*)d_in[2];
  const float* encb = (const float*)d_in[3];
  const float* decW = (const float*)d_in[4];
  const float* decb = (const float*)d_in[5];
  const float* lsg  = (const float*)d_in[6];

  float* out    = (float*)d_out;
  float* zdec   = out;                                // [2048*64]
  float* zmulti = out + N_B * D_D;                    // [8*2048*64]
  float* lse    = out + N_B * D_D + L_L * N_B * D_D;  // [1]

  float* partials = (float*)d_ws;                     // [16384*2]
  float* ez       = partials + 65536;                 // [16384]
  float* en2      = ez + 16384;                       // [16384]
  unsigned short* us = (unsigned short*)(en2 + 16384);
  unsigned short* esh = us;                 // [1048576]
  unsigned short* esl = esh + 1048576;
  unsigned short* zh  = esl + 1048576;      // [1048576]
  unsigned short* zl  = zh + 1048576;
  unsigned short* dwh = zl + 1048576;       // [32768]
  unsigned short* dwl = dwh + 32768;

  k1_prep_encode<<<400, 256, 0, stream>>>(z, e, encW, encb, decW, lsg,
                                          zmulti, esh, esl, en2,
                                          zh, zl, ez, dwh, dwl);
  lse_kernel<<<512, 256, 0, stream>>>(zh, zl, esh, esl, ez, partials);
  k3_zdec_finalize<<<129, 256, 0, stream>>>(zh, zl, dwh, dwl, decb,
                                            partials, en2, lsg,
                                            zdec, lse);
}

// Round 18
// 33.294 us; speedup vs baseline: 1.1280x; 1.0407x over previous
//
#include <hip/hip_runtime.h>
#include <math.h>

// Problem constants: N=2048, L=8, D=64, M=N=2048.
#define N_B 2048
#define L_L 8
#define D_D 64

typedef short bf16x8 __attribute__((ext_vector_type(8)));
typedef float f32x4 __attribute__((ext_vector_type(4)));
typedef unsigned short ushort8v __attribute__((ext_vector_type(8)));

#if __has_builtin(__builtin_amdgcn_exp2f)
#define EXP2(x) __builtin_amdgcn_exp2f(x)
#else
#define EXP2(x) exp2f(x)
#endif

// Async global->LDS, 16B per lane. LDS dest is wave-uniform base + lane*16;
// global src is per-lane (pre-swizzled to implement the LDS XOR swizzle).
#define GLOAD_LDS16(g, l)                                                    \
  __builtin_amdgcn_global_load_lds(                                          \
      (const __attribute__((address_space(1))) void*)(g),                    \
      (__attribute__((address_space(3))) void*)(l), 16, 0, 0)

// Split fp32 x into bf16 hi + bf16 lo (RTNE each). hi in high16, lo in low16.
__device__ __forceinline__ unsigned split_bf16_pack(float x) {
  unsigned u = __float_as_uint(x);
  unsigned rb = u + 0x7FFFu + ((u >> 16) & 1u);
  unsigned hbits = rb & 0xFFFF0000u;
  float res = x - __uint_as_float(hbits);
  unsigned u2 = __float_as_uint(res);
  unsigned rb2 = u2 + 0x7FFFu + ((u2 >> 16) & 1u);
  return hbits | (rb2 >> 16);
}

// Split 8 contiguous floats (scaled) into hi/lo ushort8 vectors.
__device__ __forceinline__ void split8(const float* __restrict__ src,
                                       float scale, ushort8v& H, ushort8v& L,
                                       float* ssq) {
  float4 v0 = *(const float4*)(src);
  float4 v1 = *(const float4*)(src + 4);
  float vv[8] = {v0.x, v0.y, v0.z, v0.w, v1.x, v1.y, v1.z, v1.w};
  #pragma unroll
  for (int t = 0; t < 8; ++t) {
    if (ssq) *ssq += vv[t] * vv[t];
    unsigned p = split_bf16_pack(scale * vv[t]);
    H[t] = (unsigned short)(p >> 16);
    L[t] = (unsigned short)(p & 0xFFFF);
  }
}

// Load 16 floats (k0..k0+7, k0+32..k0+39) from a 64-float row, split to frags.
__device__ __forceinline__ void load_split_row(const float* base, int k0,
                                               bf16x8& H0, bf16x8& L0,
                                               bf16x8& H1, bf16x8& L1) {
  float4 a0 = *(const float4*)(base + k0);
  float4 a1 = *(const float4*)(base + k0 + 4);
  float4 b0 = *(const float4*)(base + k0 + 32);
  float4 b1 = *(const float4*)(base + k0 + 36);
  float vv[16] = {a0.x, a0.y, a0.z, a0.w, a1.x, a1.y, a1.z, a1.w,
                  b0.x, b0.y, b0.z, b0.w, b1.x, b1.y, b1.z, b1.w};
  #pragma unroll
  for (int t = 0; t < 8; ++t) {
    unsigned p0 = split_bf16_pack(vv[t]);
    H0[t] = (short)(p0 >> 16); L0[t] = (short)(p0 & 0xFFFF);
    unsigned p1 = split_bf16_pack(vv[8 + t]);
    H1[t] = (short)(p1 >> 16); L1[t] = (short)(p1 & 0xFFFF);
  }
}

// ---------------------------------------------------------------------------
// K1: independent prep work in one launch — 400 blocks (proven, verbatim).
//  bid [0,128):   e-split, 128 rows/block over 4 iters, XCD-aligned (l=bid&7)
//  bid [128,384): encode (LDS-staged, split from LDS, 6 split-MFMAs)
//  bid [384,400): decW split -> dwh/dwl
// ---------------------------------------------------------------------------
__global__ __launch_bounds__(256) void k1_prep_encode(
    const float* __restrict__ z, const float* __restrict__ e,
    const float* __restrict__ encW, const float* __restrict__ encb,
    const float* __restrict__ decW, const float* __restrict__ lsg,
    float* __restrict__ zm,
    unsigned short* __restrict__ esh, unsigned short* __restrict__ esl,
    float* __restrict__ en2G,
    unsigned short* __restrict__ zhG, unsigned short* __restrict__ zlG,
    float* __restrict__ ezG,
    unsigned short* __restrict__ dwh, unsigned short* __restrict__ dwl) {
  __shared__ __align__(16) float zT[64][68];
  __shared__ __align__(16) float wT[64][68];
  const unsigned bid = blockIdx.x;
  const int tid = threadIdx.x;
  const int lane = tid & 63;
  const int wave = tid >> 6;
  const int bm = lane & 15;
  const int kg = lane >> 4;
  const int k0 = kg << 3;

  const float ls = lsg[0];
  const float sig = __expf(ls);
  const float ap = (-1.0f / (2.0f * sig * sig)) * 1.4426950408889634f;
  const float se = -2.0f * ap;

  if (bid < 128) {
    const int l = bid & 7;
    const int sub = bid >> 3;                  // 0..15
    const int rbase = l * N_B + (sub << 7);    // 128 rows
    const int c = (tid & 7) << 3;
    #pragma unroll
    for (int it = 0; it < 4; ++it) {
      const int row = rbase + (it << 5) + (tid >> 3);
      size_t off = (size_t)row * 64 + c;
      ushort8v H, L;
      float ssq = 0.f;
      split8(e + off, se, H, L, &ssq);
      *(ushort8v*)(esh + off) = H;
      *(ushort8v*)(esl + off) = L;
      ssq += __shfl_xor(ssq, 1);
      ssq += __shfl_xor(ssq, 2);
      ssq += __shfl_xor(ssq, 4);
      if ((tid & 7) == 0) en2G[row] = ssq;
    }
  } else if (bid < 384) {
    const int eb = bid - 128;
    const int l = eb & 7;
    const int nt = eb >> 3;
    const int n0 = nt << 6;
    {
      int r = tid >> 2, q = (tid & 3) << 4;
      const float4* zsrc = (const float4*)(z + (size_t)(n0 + r) * 64 + q);
      const float4* wsrc = (const float4*)(encW + (size_t)(l * 64 + r) * 64 + q);
      #pragma unroll
      for (int j = 0; j < 4; ++j) {
        *(float4*)&zT[r][q + j * 4] = zsrc[j];
        *(float4*)&wT[r][q + j * 4] = wsrc[j];
      }
    }
    __syncthreads();
    bf16x8 Bh0[4], Bh1[4], Bl0[4], Bl1[4];
    #pragma unroll
    for (int ms = 0; ms < 4; ++ms)
      load_split_row(&wT[ms * 16 + bm][0], k0,
                     Bh0[ms], Bl0[ms], Bh1[ms], Bl1[ms]);
    bf16x8 ah0, al0, ah1, al1;
    load_split_row(&zT[(wave << 4) + bm][0], k0, ah0, al0, ah1, al1);

    float sq[4] = {0.f, 0.f, 0.f, 0.f};
    #pragma unroll
    for (int ms = 0; ms < 4; ++ms) {
      float bi = encb[l * 64 + ms * 16 + bm];
      f32x4 acc = {bi, bi, bi, bi};
      acc = __builtin_amdgcn_mfma_f32_16x16x32_bf16(ah0, Bh0[ms], acc, 0, 0, 0);
      acc = __builtin_amdgcn_mfma_f32_16x16x32_bf16(ah1, Bh1[ms], acc, 0, 0, 0);
      acc = __builtin_amdgcn_mfma_f32_16x16x32_bf16(al0, Bh0[ms], acc, 0, 0, 0);
      acc = __builtin_amdgcn_mfma_f32_16x16x32_bf16(al1, Bh1[ms], acc, 0, 0, 0);
      acc = __builtin_amdgcn_mfma_f32_16x16x32_bf16(ah0, Bl0[ms], acc, 0, 0, 0);
      acc = __builtin_amdgcn_mfma_f32_16x16x32_bf16(ah1, Bl1[ms], acc, 0, 0, 0);
      #pragma unroll
      for (int r = 0; r < 4; ++r) {
        float v = acc[r];
        int nr = n0 + (wave << 4) + (kg << 2) + r;
        size_t idx = ((size_t)(l * N_B + nr)) * 64 + (ms << 4) + bm;
        zm[idx] = v;
        unsigned p = split_bf16_pack(v);
        zhG[idx] = (unsigned short)(p >> 16);
        zlG[idx] = (unsigned short)(p & 0xFFFF);
        sq[r] += v * v;
      }
    }
    #pragma unroll
    for (int r = 0; r < 4; ++r) {
      float s = sq[r];
      s += __shfl_xor(s, 1);
      s += __shfl_xor(s, 2);
      s += __shfl_xor(s, 4);
      s += __shfl_xor(s, 8);
      if (bm == 0)
        ezG[l * N_B + n0 + (wave << 4) + (kg << 2) + r] = EXP2(ap * s);
    }
  } else {
    int t = (bid - 384) * 256 + tid;  // 0..4095
    size_t off = (size_t)t * 8;
    ushort8v H, L;
    split8(decW + off, 1.0f, H, L, nullptr);
    *(ushort8v*)(dwh + off) = H;
    *(ushort8v*)(dwl + off) = L;
  }
}

// ---------------------------------------------------------------------------
// K2: bid<512: lse (proven round-15/17 body, XCD-swizzled, double-buffered
//     global_load_lds staging, XOR swizzle) -> partials;
//     bid>=512: zdec (depends only on K1; tail-fills as lse blocks drain).
// Shared-memory union pool (33KB) keeps lse occupancy at 4 blocks/CU.
// ---------------------------------------------------------------------------
__global__ __launch_bounds__(256, 4) void k2_lse_zdec(
    const unsigned short* __restrict__ zhG, const unsigned short* __restrict__ zlG,
    const unsigned short* __restrict__ esh, const unsigned short* __restrict__ esl,
    const float* __restrict__ ezG,
    const unsigned short* __restrict__ dwh, const unsigned short* __restrict__ dwl,
    const float* __restrict__ decb,
    float* __restrict__ partials, float* __restrict__ zdec) {
  __shared__ __align__(16) unsigned char pool[33792];  // union: lse 33KB/zdec 16KB
  const unsigned bid = blockIdx.x;
  const int tid = threadIdx.x;
  const int lane = tid & 63;
  const int wave = tid >> 6;
  const int bm = lane & 15;
  const int kg = lane >> 4;
  const int k0 = kg << 3;

  if (bid < 512) {
    unsigned short(*zbh)[4096] = (unsigned short(*)[4096])pool;
    unsigned short(*zbl)[4096] = (unsigned short(*)[4096])(pool + 16384);
    float(*red)[64] = (float(*)[64])(pool + 32768);

    const int wgid = (bid & 7) * 64 + (bid >> 3);  // XCD swizzle
    const int l = wgid >> 6;
    const int mt = (wgid >> 1) & 31;
    const int nb = wgid & 1;
    const int m0 = mt << 6;

    // ---- B fragments: pre-split scaled e rows (held in registers) ----
    bf16x8 Bh0[4], Bh1[4], Bl0[4], Bl1[4];
    #pragma unroll
    for (int ms = 0; ms < 4; ++ms) {
      size_t base = ((size_t)(l * N_B) + m0 + ms * 16 + bm) * 64 + k0;
      Bh0[ms] = *(const bf16x8*)(esh + base);
      Bh1[ms] = *(const bf16x8*)(esh + base + 32);
      Bl0[ms] = *(const bf16x8*)(esl + base);
      Bl1[ms] = *(const bf16x8*)(esl + base + 32);
    }

    // ---- staging geometry (constant across c) ----
    const int srow0 = (wave << 4) + (lane >> 3);
    const size_t g0 = (size_t)srow0 * 64 + (((lane & 7) ^ (lane >> 3)) << 3);
    const size_t g1 = g0 + 8 * 64;  // +8 rows, same swizzle (row&7 unchanged)
    const int ldsb0 = (wave << 4) * 64;           // elems, uniform per wave
    const unsigned short* zhT =
        zhG + ((size_t)(l * N_B) + (nb << 10)) * 64;  // tile base
    const unsigned short* zlT = zlG + ((size_t)(l * N_B) + (nb << 10)) * 64;

    auto stage = [&](int b, int c) {
      size_t toff = (size_t)(c << 6) * 64;  // c*64 rows
      GLOAD_LDS16(zhT + toff + g0, &zbh[b][ldsb0]);
      GLOAD_LDS16(zhT + toff + g1, &zbh[b][ldsb0 + 512]);
      GLOAD_LDS16(zlT + toff + g0, &zbl[b][ldsb0]);
      GLOAD_LDS16(zlT + toff + g1, &zbl[b][ldsb0 + 512]);
    };

    // ---- A-fragment LDS read offsets (XOR-swizzled) ----
    const int arow = (wave << 4) + bm;
    const int sw = (bm & 7) << 3;
    const int o0 = arow * 64 + ((kg << 3) ^ sw);
    const int o1 = arow * 64 + (((kg << 3) + 32) ^ sw);

    float sums[4] = {0.f, 0.f, 0.f, 0.f};
    const float* ezQ = ezG + l * N_B + (nb << 10) + (wave << 4) + (kg << 2);

    stage(0, 0);
    f32x4 ezv = *(const f32x4*)(ezQ);

    int cur = 0;
    #pragma unroll 1
    for (int c = 0; c < 16; ++c) {
      __syncthreads();  // tile c staged; prior-iter LDS reads retired
      bf16x8 ah0 = *(const bf16x8*)&zbh[cur][o0];
      bf16x8 ah1 = *(const bf16x8*)&zbh[cur][o1];
      bf16x8 al0 = *(const bf16x8*)&zbl[cur][o0];
      bf16x8 al1 = *(const bf16x8*)&zbl[cur][o1];
      f32x4 eznext = ezv;
      if (c < 15) {
        stage(cur ^ 1, c + 1);          // async; drains at next iter's barrier
        eznext = *(const f32x4*)(ezQ + ((c + 1) << 6));
      }
      #pragma unroll
      for (int ms = 0; ms < 4; ++ms) {
        f32x4 acc = {0.f, 0.f, 0.f, 0.f};
        acc = __builtin_amdgcn_mfma_f32_16x16x32_bf16(ah0, Bh0[ms], acc, 0, 0, 0);
        acc = __builtin_amdgcn_mfma_f32_16x16x32_bf16(ah1, Bh1[ms], acc, 0, 0, 0);
        acc = __builtin_amdgcn_mfma_f32_16x16x32_bf16(al0, Bh0[ms], acc, 0, 0, 0);
        acc = __builtin_amdgcn_mfma_f32_16x16x32_bf16(al1, Bh1[ms], acc, 0, 0, 0);
        acc = __builtin_amdgcn_mfma_f32_16x16x32_bf16(ah0, Bl0[ms], acc, 0, 0, 0);
        acc = __builtin_amdgcn_mfma_f32_16x16x32_bf16(ah1, Bl1[ms], acc, 0, 0, 0);
        sums[ms] = fmaf(ezv[0], EXP2(acc[0]), sums[ms]);
        sums[ms] = fmaf(ezv[1], EXP2(acc[1]), sums[ms]);
        sums[ms] = fmaf(ezv[2], EXP2(acc[2]), sums[ms]);
        sums[ms] = fmaf(ezv[3], EXP2(acc[3]), sums[ms]);
      }
      ezv = eznext;
      cur ^= 1;
    }

    #pragma unroll
    for (int ms = 0; ms < 4; ++ms) {
      float s = sums[ms];
      s += __shfl_xor(s, 16);
      s += __shfl_xor(s, 32);
      if (lane < 16) red[wave][ms * 16 + lane] = s;
    }
    __syncthreads();
    if (tid < 64) {
      float S = red[0][tid] + red[1][tid] + red[2][tid] + red[3][tid];
      partials[((((size_t)(l * N_B)) + m0 + tid) << 1) + nb] = S;
    }
  } else {
    // ---- zdec: tail-fills after lse blocks ----
    f32x4(*redq)[4][64] = (f32x4(*)[4][64])pool;
    const int n0 = (int)(bid - 512) << 4;
    f32x4 acc[4] = {{0.f, 0.f, 0.f, 0.f}, {0.f, 0.f, 0.f, 0.f},
                    {0.f, 0.f, 0.f, 0.f}, {0.f, 0.f, 0.f, 0.f}};
    #pragma unroll
    for (int jj = 0; jj < 4; ++jj) {
      int j = (wave << 2) + jj;
      int l = j >> 1;
      int off = ((j & 1) << 5) + k0;
      size_t ab = ((size_t)(l * N_B + n0 + bm)) * 64 + off;
      bf16x8 ah = *(const bf16x8*)(zhG + ab);
      bf16x8 al = *(const bf16x8*)(zlG + ab);
      #pragma unroll
      for (int ms = 0; ms < 4; ++ms) {
        int d = (ms << 4) + bm;
        size_t bb = (size_t)d * 512 + (j << 5) + k0;
        bf16x8 bh = *(const bf16x8*)(dwh + bb);
        bf16x8 bl = *(const bf16x8*)(dwl + bb);
        acc[ms] = __builtin_amdgcn_mfma_f32_16x16x32_bf16(ah, bh, acc[ms], 0, 0, 0);
        acc[ms] = __builtin_amdgcn_mfma_f32_16x16x32_bf16(al, bh, acc[ms], 0, 0, 0);
        acc[ms] = __builtin_amdgcn_mfma_f32_16x16x32_bf16(ah, bl, acc[ms], 0, 0, 0);
      }
    }
    #pragma unroll
    for (int ms = 0; ms < 4; ++ms) redq[wave][ms][lane] = acc[ms];
    __syncthreads();
    if (wave == 0) {
      #pragma unroll
      for (int ms = 0; ms < 4; ++ms) {
        f32x4 s = redq[0][ms][lane];
        #pragma unroll
        for (int w = 1; w < 4; ++w) {
          f32x4 t = redq[w][ms][lane];
          s[0] += t[0]; s[1] += t[1]; s[2] += t[2]; s[3] += t[3];
        }
        float bd = decb[(ms << 4) + bm];
        #pragma unroll
        for (int r = 0; r < 4; ++r)
          zdec[(size_t)(n0 + (kg << 2) + r) * 64 + (ms << 4) + bm] = s[r] + bd;
      }
    }
  }
}

// ---------------------------------------------------------------------------
// K3: single-block finalize (only true dependent of K2's partials).
// ---------------------------------------------------------------------------
__global__ __launch_bounds__(256) void k3_finalize(
    const float* __restrict__ partials, const float* __restrict__ en2G,
    const float* __restrict__ lsg, float* __restrict__ out_scalar) {
  __shared__ float buf[4];
  const int tid = threadIdx.x;
  const int lane = tid & 63;
  const int wave = tid >> 6;
  const float ls = lsg[0];
  const float sig = __expf(ls);
  const float ap = (-1.0f / (2.0f * sig * sig)) * 1.4426950408889634f;
  float local = 0.f;
  #pragma unroll 4
  for (int i = 0; i < 32; ++i) {
    int idx2 = (tid + (i << 8)) << 1;  // rows 2t, partials [row][2]
    f32x4 p = *(const f32x4*)(partials + idx2 * 2);  // rows 2t..2t+1
    float2 e2 = *(const float2*)(en2G + idx2);
    local += ap * e2.x + __log2f(p[0] + p[1]);
    local += ap * e2.y + __log2f(p[2] + p[3]);
  }
  #pragma unroll
  for (int off = 32; off; off >>= 1) local += __shfl_down(local, off);
  if (lane == 0) buf[wave] = local;
  __syncthreads();
  if (tid == 0) {
    float t = buf[0] + buf[1] + buf[2] + buf[3];
    float total = 0.69314718055994531f * t;
    float val = -total / (float)(L_L * N_B)
              + 0.5f * (float)D_D * (2.0f * ls - 1.0f)
              + logf((float)N_B);
    *out_scalar = val;
  }
}

extern "C" void kernel_launch(void* const* d_in, const int* in_sizes, int n_in,
                              void* d_out, int out_size, void* d_ws, size_t ws_size,
                              hipStream_t stream) {
  const float* z    = (const float*)d_in[0];
  const float* e    = (const float*)d_in[1];
  const float* encW = (const float*)d_in[2];
  const float* encb = (const float*)d_in[3];
  const float* decW = (const float*)d_in[4];
  const float* decb = (const float*)d_in[5];
  const float* lsg  = (const float*)d_in[6];

  float* out    = (float*)d_out;
  float* zdec   = out;                                // [2048*64]
  float* zmulti = out + N_B * D_D;                    // [8*2048*64]
  float* lse    = out + N_B * D_D + L_L * N_B * D_D;  // [1]

  float* partials = (float*)d_ws;                     // [16384*2]
  float* ez       = partials + 65536;                 // [16384]
  float* en2      = ez + 16384;                       // [16384]
  unsigned short* us = (unsigned short*)(en2 + 16384);
  unsigned short* esh = us;                 // [1048576]
  unsigned short* esl = esh + 1048576;
  unsigned short* zh  = esl + 1048576;      // [1048576]
  unsigned short* zl  = zh + 1048576;
  unsigned short* dwh = zl + 1048576;       // [32768]
  unsigned short* dwl = dwh + 32768;

  k1_prep_encode<<<400, 256, 0, stream>>>(z, e, encW, encb, decW, lsg,
                                          zmulti, esh, esl, en2,
                                          zh, zl, ez, dwh, dwl);
  k2_lse_zdec<<<640, 256, 0, stream>>>(zh, zl, esh, esl, ez,
                                       dwh, dwl, decb, partials, zdec);
  k3_finalize<<<1, 256, 0, stream>>>(partials, en2, lsg, lse);
}